// Round 2
// baseline (1030.318 us; speedup 1.0000x reference)
//
#include <hip/hip_runtime.h>
#include <hip/hip_bf16.h>

#define NB 8
#define NA 100000
#define NC 90
#define MAXDET 100
#define KCAND 2048
#define NBINS 4096
#define CONF 0.25f
#define IOUT 0.45f

// ---- workspace layout (bytes) ----
static constexpr size_t OFF_BOX   = 0;                                          // B*N*4 f32
static constexpr size_t OFF_SCORE = OFF_BOX   + (size_t)NB*NA*4*sizeof(float);  // B*N f32
static constexpr size_t OFF_LABEL = OFF_SCORE + (size_t)NB*NA*sizeof(float);    // B*N i32
static constexpr size_t OFF_HIST  = OFF_LABEL + (size_t)NB*NA*sizeof(int);      // B*4096 u32
static constexpr size_t OFF_THR   = OFF_HIST  + (size_t)NB*NBINS*sizeof(unsigned); // B u32 (padded)
static constexpr size_t OFF_CNT   = OFF_THR   + 64;                             // B u32 (padded)
static constexpr size_t OFF_CKEY  = OFF_CNT   + 64;                             // B*KCAND u64
static constexpr size_t OFF_CBOX  = OFF_CKEY  + (size_t)NB*KCAND*8;             // B*KCAND f32x4
static constexpr size_t OFF_CLAB  = OFF_CBOX  + (size_t)NB*KCAND*16;            // B*KCAND i32
// total ~19.8 MB

__global__ void k_zero(unsigned* hist, unsigned* cnt) {
    int i = blockIdx.x * blockDim.x + threadIdx.x;
    if (i < NB * NBINS) hist[i] = 0u;
    if (i < NB) cnt[i] = 0u;
}

__device__ __forceinline__ float4 decode_clip(float4 a, float4 r) {
#pragma clang fp contract(off)
    // a = (y1,x1,y2,x2) anchor; r = (dy,dx,dh,dw)
    float yca = (a.x + a.z) * 0.5f;
    float xca = (a.y + a.w) * 0.5f;
    float ha  = a.z - a.x;
    float wa  = a.w - a.y;
    float w   = expf(r.w) * wa;
    float h   = expf(r.z) * ha;
    float yc  = r.x * ha + yca;
    float xc  = r.y * wa + xca;
    float x1  = xc - w * 0.5f, y1 = yc - h * 0.5f;
    float x2  = xc + w * 0.5f, y2 = yc + h * 0.5f;
    x1 = fminf(fmaxf(x1, 0.0f), 512.0f);
    x2 = fminf(fmaxf(x2, 0.0f), 512.0f);
    y1 = fminf(fmaxf(y1, 0.0f), 512.0f);
    y2 = fminf(fmaxf(y2, 0.0f), 512.0f);
    return make_float4(x1, y1, x2, y2);  // (x1,y1,x2,y2) like reference
}

// One thread per (b,n): sigmoid max/argmax over 90 classes, box decode, histogram.
__global__ void k_score_box(const float* __restrict__ cls,
                            const float* __restrict__ reg,
                            const float* __restrict__ anc,
                            float4* __restrict__ ws_box,
                            float* __restrict__ ws_score,
                            int* __restrict__ ws_label,
                            unsigned* __restrict__ hist) {
    int idx = blockIdx.x * blockDim.x + threadIdx.x;
    if (idx >= NB * NA) return;
    int b = idx / NA;
    int n = idx - b * NA;

    const float2* p2 = (const float2*)(cls + (size_t)idx * NC);  // 360B stride, 8B aligned
    float best = -1.0f;
    int lab = 0;
    for (int j = 0; j < NC / 2; ++j) {
        float2 v = p2[j];
        float sa = 1.0f / (1.0f + expf(-v.x));  // sigmoid-domain compare == jnp semantics
        float sb = 1.0f / (1.0f + expf(-v.y));
        if (sa > best) { best = sa; lab = 2 * j; }
        if (sb > best) { best = sb; lab = 2 * j + 1; }
    }
    ws_score[idx] = best;
    ws_label[idx] = lab;

    float4 a = ((const float4*)anc)[n];
    float4 r = ((const float4*)reg)[idx];
    ws_box[idx] = decode_clip(a, r);

    if (best > CONF) {
        int bin = (int)(best * (float)NBINS);
        if (bin > NBINS - 1) bin = NBINS - 1;
        atomicAdd(&hist[b * NBINS + bin], 1u);
    }
}

// Single block: per image, smallest bin b* with suffix-count S(b*) <= KCAND.
__global__ void k_thresh(const unsigned* __restrict__ hist, unsigned* __restrict__ thr_bin) {
    __shared__ unsigned chunk[256];
    __shared__ int bstar;
    int t = threadIdx.x;
    for (int b = 0; b < NB; ++b) {
        const unsigned* h = hist + b * NBINS;
        unsigned s = 0;
        for (int j = 0; j < 16; ++j) s += h[t * 16 + j];
        chunk[t] = s;
        if (t == 0) bstar = NBINS - 1;
        __syncthreads();
        unsigned U = 0;  // sum of chunks strictly after t
        for (int j = t + 1; j < 256; ++j) U += chunk[j];
        unsigned run = U;
        int cand = NBINS;  // min bin in this chunk with S(bin) <= KCAND
        for (int j = 15; j >= 0; --j) {
            run += h[t * 16 + j];
            if (run <= (unsigned)KCAND) cand = t * 16 + j;
        }
        if (cand < NBINS) atomicMin(&bstar, cand);
        __syncthreads();
        if (t == 0) thr_bin[b] = (unsigned)bstar;
        __syncthreads();
    }
}

__global__ void k_compact(const float* __restrict__ ws_score,
                          const int* __restrict__ ws_label,
                          const float4* __restrict__ ws_box,
                          const unsigned* __restrict__ thr_bin,
                          unsigned* __restrict__ cnt,
                          unsigned long long* __restrict__ ckey,
                          float4* __restrict__ cbox,
                          int* __restrict__ clab) {
    int idx = blockIdx.x * blockDim.x + threadIdx.x;
    if (idx >= NB * NA) return;
    int b = idx / NA;
    int n = idx - b * NA;
    float s = ws_score[idx];
    if (s > CONF) {
        int bin = (int)(s * (float)NBINS);
        if (bin > NBINS - 1) bin = NBINS - 1;
        if ((unsigned)bin >= thr_bin[b]) {
            unsigned pos = atomicAdd(&cnt[b], 1u);
            if (pos < KCAND) {
                // key: score bits (s>0 so monotone) high, ~idx low -> max key = highest score, ties -> lowest n
                unsigned long long key =
                    ((unsigned long long)__float_as_uint(s) << 32) |
                    (unsigned long long)(0xFFFFFFFFu - (unsigned)n);
                ckey[b * KCAND + pos] = key;
                cbox[b * KCAND + pos] = ws_box[idx];
                clab[b * KCAND + pos] = ws_label[idx];
            }
        }
    }
}

// One block per image: exact greedy NMS over <=2048 candidates in LDS.
// Outputs are FLOAT32: scores [0,800), labels-as-float [800,1600), boxes [1600,4800).
__global__ __launch_bounds__(512) void k_nms(const unsigned long long* __restrict__ ckey,
                                             const float4* __restrict__ cbox,
                                             const int* __restrict__ clab,
                                             const unsigned* __restrict__ cnt,
                                             float* __restrict__ out) {
    __shared__ unsigned long long key[KCAND];
    __shared__ float4 box[KCAND];
    __shared__ int lab[KCAND];
    __shared__ unsigned long long wmax[8];
    __shared__ unsigned long long bestkey_s;
    __shared__ int bestslot_s;
    __shared__ float4 bestbox_s;

    int b = blockIdx.x;
    int t = threadIdx.x;
    unsigned M = cnt[b];
    if (M > (unsigned)KCAND) M = KCAND;

    for (int j = t; j < KCAND; j += 512) {
        if (j < (int)M) {
            key[j] = ckey[b * KCAND + j];
            box[j] = cbox[b * KCAND + j];
            lab[j] = clab[b * KCAND + j];
        } else {
            key[j] = 0ULL;
        }
    }
    __syncthreads();

    for (int k = 0; k < MAXDET; ++k) {
        // ---- argmax over keys ----
        unsigned long long m = 0ULL;
#pragma unroll
        for (int s = 0; s < KCAND / 512; ++s) {
            unsigned long long v = key[t + s * 512];
            if (v > m) m = v;
        }
        for (int off = 32; off > 0; off >>= 1) {
            unsigned long long o = __shfl_down(m, off);
            if (o > m) m = o;
        }
        if ((t & 63) == 0) wmax[t >> 6] = m;
        __syncthreads();
        if (t == 0) {
            unsigned long long mm = 0ULL;
            for (int w = 0; w < 8; ++w)
                if (wmax[w] > mm) mm = wmax[w];
            bestkey_s = mm;
            bestslot_s = 0;
        }
        __syncthreads();
        unsigned long long bk = bestkey_s;
        if (bk != 0ULL) {
#pragma unroll
            for (int s = 0; s < KCAND / 512; ++s) {
                int j = t + s * 512;
                if (key[j] == bk) bestslot_s = j;  // unique writer (idx in key)
            }
        }
        __syncthreads();
        bool valid = (bk >> 32) != 0ULL;  // real candidates have score>0.25
        int bs = bestslot_s;
        if (t == 0) {
            float sc;
            float lb;
            float4 bb;
            if (valid) { sc = __uint_as_float((unsigned)(bk >> 32)); lb = (float)lab[bs]; bb = box[bs]; }
            else       { sc = 0.0f; lb = -1.0f; bb = make_float4(0.f, 0.f, 0.f, 0.f); }
            out[b * MAXDET + k] = sc;
            out[NB * MAXDET + b * MAXDET + k] = lb;
            float* ob = out + 2 * NB * MAXDET + (size_t)(b * MAXDET + k) * 4;
            ob[0] = bb.x;
            ob[1] = bb.y;
            ob[2] = bb.z;
            ob[3] = bb.w;
            bestbox_s = bb;
        }
        __syncthreads();
        if (valid) {
#pragma clang fp contract(off)
            float4 bb = bestbox_s;
            float areaB = (bb.z - bb.x) * (bb.w - bb.y);
#pragma unroll
            for (int s = 0; s < KCAND / 512; ++s) {
                int j = t + s * 512;
                unsigned long long kj = key[j];
                if (kj != 0ULL) {
                    float4 bj = box[j];
                    float x1 = fmaxf(bb.x, bj.x), y1 = fmaxf(bb.y, bj.y);
                    float x2 = fminf(bb.z, bj.z), y2 = fminf(bb.w, bj.w);
                    float inter = fmaxf(x2 - x1, 0.0f) * fmaxf(y2 - y1, 0.0f);
                    float areaJ = (bj.z - bj.x) * (bj.w - bj.y);
                    float iou = inter / (areaB + areaJ - inter + 1e-8f);
                    if (iou > IOUT) key[j] = 0ULL;
                }
            }
            if (t == 0) key[bs] = 0ULL;  // reference always kills the selected slot
        }
        __syncthreads();
    }
}

extern "C" void kernel_launch(void* const* d_in, const int* in_sizes, int n_in,
                              void* d_out, int out_size, void* d_ws, size_t ws_size,
                              hipStream_t stream) {
    const float* reg = (const float*)d_in[0];  // [8,100000,4]
    const float* cls = (const float*)d_in[1];  // [8,100000,90]
    const float* anc = (const float*)d_in[2];  // [1,100000,4]
    // d_in[3] imgs: only shape (512,512) used, hard-coded.

    char* ws = (char*)d_ws;
    float4* ws_box            = (float4*)(ws + OFF_BOX);
    float* ws_score           = (float*)(ws + OFF_SCORE);
    int* ws_label             = (int*)(ws + OFF_LABEL);
    unsigned* hist            = (unsigned*)(ws + OFF_HIST);
    unsigned* thr_bin         = (unsigned*)(ws + OFF_THR);
    unsigned* cnt             = (unsigned*)(ws + OFF_CNT);
    unsigned long long* ckey  = (unsigned long long*)(ws + OFF_CKEY);
    float4* cbox              = (float4*)(ws + OFF_CBOX);
    int* clab                 = (int*)(ws + OFF_CLAB);

    float* out = (float*)d_out;

    k_zero<<<(NB * NBINS + 255) / 256, 256, 0, stream>>>(hist, cnt);
    k_score_box<<<(NB * NA + 255) / 256, 256, 0, stream>>>(cls, reg, anc, ws_box, ws_score,
                                                           ws_label, hist);
    k_thresh<<<1, 256, 0, stream>>>(hist, thr_bin);
    k_compact<<<(NB * NA + 255) / 256, 256, 0, stream>>>(ws_score, ws_label, ws_box, thr_bin, cnt,
                                                         ckey, cbox, clab);
    k_nms<<<NB, 512, 0, stream>>>(ckey, cbox, clab, cnt, out);
}

// Round 3
// 694.054 us; speedup vs baseline: 1.4845x; 1.4845x over previous
//
#include <hip/hip_runtime.h>

#define NB 8
#define NA 100000
#define NC 90
#define MAXDET 100
#define KCAND 2048
#define NBINS 4096
#define NBLK 13        // hist/compact blocks per image
#define BLK_ANCH 8000  // anchors per hist/compact block
#define CONF 0.25f
#define IOUT 0.45f

// ---- workspace layout (bytes), total ~18.1 MiB (round-2 layout proved >= this) ----
static constexpr size_t OFF_BOX   = 0;                                            // NB*NA float4
static constexpr size_t OFF_SCORE = OFF_BOX   + (size_t)NB * NA * 16;             // NB*NA f32
static constexpr size_t OFF_LABEL = OFF_SCORE + (size_t)NB * NA * 4;              // NB*NA u8
static constexpr size_t OFF_HROWS = OFF_LABEL + (size_t)NB * NA;                  // NB*NBLK*NBINS u32
static constexpr size_t OFF_THR   = OFF_HROWS + (size_t)NB * NBLK * NBINS * 4;    // NB u32 (pad 64)
static constexpr size_t OFF_CNT   = OFF_THR   + 64;                               // NB u32 (pad 64)
static constexpr size_t OFF_CKEY  = OFF_CNT   + 64;                               // NB*KCAND u64
static constexpr size_t OFF_CBOX  = OFF_CKEY  + (size_t)NB * KCAND * 8;           // NB*KCAND float4
static constexpr size_t OFF_CLAB  = OFF_CBOX  + (size_t)NB * KCAND * 16;          // NB*KCAND i32

__device__ __forceinline__ float4 decode_clip(float4 a, float4 r) {
#pragma clang fp contract(off)
    // a = (y1,x1,y2,x2) anchor; r = (dy,dx,dh,dw)
    float yca = (a.x + a.z) * 0.5f;
    float xca = (a.y + a.w) * 0.5f;
    float ha  = a.z - a.x;
    float wa  = a.w - a.y;
    float w   = expf(r.w) * wa;
    float h   = expf(r.z) * ha;
    float yc  = r.x * ha + yca;
    float xc  = r.y * wa + xca;
    float x1  = xc - w * 0.5f, y1 = yc - h * 0.5f;
    float x2  = xc + w * 0.5f, y2 = yc + h * 0.5f;
    x1 = fminf(fmaxf(x1, 0.0f), 512.0f);
    x2 = fminf(fmaxf(x2, 0.0f), 512.0f);
    y1 = fminf(fmaxf(y1, 0.0f), 512.0f);
    y2 = fminf(fmaxf(y2, 0.0f), 512.0f);
    return make_float4(x1, y1, x2, y2);
}

// 16 lanes per anchor: coalesced 64B class segments; shfl-xor argmax in sigmoid domain.
// Tie-break packed as (89-j) in low bits -> max key == first (lowest-class) max, jnp semantics.
__global__ __launch_bounds__(256) void k_score_box(const float* __restrict__ cls,
                                                   const float* __restrict__ reg,
                                                   const float* __restrict__ anc,
                                                   float4* __restrict__ ws_box,
                                                   float* __restrict__ ws_score,
                                                   unsigned char* __restrict__ ws_label) {
    int tid = threadIdx.x;
    int grp = tid >> 4;
    int lane = tid & 15;
    int a_idx = blockIdx.x * 16 + grp;  // < 800000, grid sized exactly

    const float* p = cls + (size_t)a_idx * NC;
    unsigned long long best = 0ULL;
#pragma unroll
    for (int t = 0; t < 6; ++t) {
        int j = lane + 16 * t;
        if (j < NC) {
            float x = p[j];
            float s = 1.0f / (1.0f + expf(-x));  // same formula as verified round-2 kernel
            unsigned long long key = ((unsigned long long)__float_as_uint(s) << 32) |
                                     (unsigned long long)(unsigned)(NC - 1 - j);
            if (key > best) best = key;
        }
    }
#pragma unroll
    for (int off = 8; off >= 1; off >>= 1) {
        unsigned long long o = __shfl_xor(best, off, 16);
        if (o > best) best = o;
    }
    if (lane == 0) {
        ws_score[a_idx] = __uint_as_float((unsigned)(best >> 32));
        ws_label[a_idx] = (unsigned char)(NC - 1 - (int)(best & 0xFFFFFFFFu));
    }

    if (tid < 16) {
        int idx = blockIdx.x * 16 + tid;
        int n = idx % NA;
        float4 a = ((const float4*)anc)[n];
        float4 r = ((const float4*)reg)[idx];
        ws_box[idx] = decode_clip(a, r);
    }
}

// Per-block LDS histogram, full-row writeout (no global atomics).
__global__ __launch_bounds__(256) void k_hist(const float* __restrict__ ws_score,
                                              unsigned* __restrict__ hrows) {
    __shared__ unsigned h[NBINS];
    int b = blockIdx.y, blk = blockIdx.x, tid = threadIdx.x;
    for (int i = tid; i < NBINS; i += 256) h[i] = 0u;
    __syncthreads();
    int base = blk * BLK_ANCH;
    int lim = min(BLK_ANCH, NA - base);
    const float* sc = ws_score + (size_t)b * NA + base;
    for (int i = tid; i < lim; i += 256) {
        float s = sc[i];
        if (s > CONF) {
            int bin = min((int)(s * (float)NBINS), NBINS - 1);
            atomicAdd(&h[bin], 1u);
        }
    }
    __syncthreads();
    unsigned* row = hrows + ((size_t)b * NBLK + blk) * NBINS;
    for (int i = tid; i < NBINS; i += 256) row[i] = h[i];
}

// One block per image: reduce rows, find min bin with suffix-count <= KCAND; zero cnt.
__global__ __launch_bounds__(256) void k_thresh(const unsigned* __restrict__ hrows,
                                                unsigned* __restrict__ thr_bin,
                                                unsigned* __restrict__ cnt) {
    __shared__ unsigned h[NBINS];
    __shared__ unsigned chunk[256];
    __shared__ int bstar;
    int b = blockIdx.x, t = threadIdx.x;
    for (int i = t; i < NBINS; i += 256) {
        unsigned s = 0;
        for (int r = 0; r < NBLK; ++r) s += hrows[((size_t)b * NBLK + r) * NBINS + i];
        h[i] = s;
    }
    if (t == 0) { bstar = NBINS - 1; cnt[b] = 0u; }
    __syncthreads();
    unsigned s = 0;
    for (int j = 0; j < 16; ++j) s += h[t * 16 + j];
    chunk[t] = s;
    __syncthreads();
    unsigned U = 0;
    for (int j = t + 1; j < 256; ++j) U += chunk[j];
    unsigned run = U;
    int cand = NBINS;
    for (int j = 15; j >= 0; --j) {
        run += h[t * 16 + j];
        if (run <= (unsigned)KCAND) cand = t * 16 + j;
    }
    if (cand < NBINS) atomicMin(&bstar, cand);
    __syncthreads();
    if (t == 0) thr_bin[b] = (unsigned)bstar;
}

// Block-aggregated compaction: LDS prefix scan, ONE global atomic per block (13/image).
__global__ __launch_bounds__(256) void k_compact(const float* __restrict__ ws_score,
                                                 const unsigned char* __restrict__ ws_label,
                                                 const float4* __restrict__ ws_box,
                                                 const unsigned* __restrict__ thr_bin,
                                                 unsigned* __restrict__ cnt,
                                                 unsigned long long* __restrict__ ckey,
                                                 float4* __restrict__ cbox,
                                                 int* __restrict__ clab) {
    __shared__ unsigned scan[256];
    __shared__ unsigned base_s;
    int b = blockIdx.y, blk = blockIdx.x, t = threadIdx.x;
    int base = blk * BLK_ANCH;
    int lim = min(BLK_ANCH, NA - base);
    size_t ibase = (size_t)b * NA + base;
    unsigned thr = thr_bin[b];

    unsigned c = 0;
    for (int i = t; i < lim; i += 256) {
        float s = ws_score[ibase + i];
        if (s > CONF) {
            int bin = min((int)(s * (float)NBINS), NBINS - 1);
            if ((unsigned)bin >= thr) c++;
        }
    }
    scan[t] = c;
    __syncthreads();
    for (int off = 1; off < 256; off <<= 1) {
        unsigned v = (t >= off) ? scan[t - off] : 0u;
        __syncthreads();
        scan[t] += v;
        __syncthreads();
    }
    if (t == 255) base_s = atomicAdd(&cnt[b], scan[255]);
    __syncthreads();
    unsigned pos = base_s + scan[t] - c;  // exclusive prefix for this thread
    for (int i = t; i < lim; i += 256) {
        float s = ws_score[ibase + i];
        if (s > CONF) {
            int bin = min((int)(s * (float)NBINS), NBINS - 1);
            if ((unsigned)bin >= thr) {
                unsigned p = pos++;
                if (p < (unsigned)KCAND) {
                    int n = base + i;
                    ckey[(size_t)b * KCAND + p] =
                        ((unsigned long long)__float_as_uint(s) << 32) |
                        (unsigned long long)(0xFFFFFFFFu - (unsigned)n);
                    cbox[(size_t)b * KCAND + p] = ws_box[ibase + i];
                    clab[(size_t)b * KCAND + p] = (int)ws_label[ibase + i];
                }
            }
        }
    }
}

// One block per image: exact greedy NMS in LDS; 3 barriers/iter; outputs buffered in LDS.
__global__ __launch_bounds__(256) void k_nms(const unsigned long long* __restrict__ ckey,
                                             const float4* __restrict__ cbox,
                                             const int* __restrict__ clab,
                                             const unsigned* __restrict__ cnt,
                                             float* __restrict__ out) {
    __shared__ unsigned long long key[KCAND];
    __shared__ float4 box[KCAND];
    __shared__ int lab[KCAND];
    __shared__ unsigned long long bestkey;
    __shared__ float4 bestbox;
    __shared__ int bestlab;
    __shared__ float out_s[MAXDET];
    __shared__ float out_l[MAXDET];
    __shared__ float4 out_b[MAXDET];

    int b = blockIdx.x, t = threadIdx.x;
    unsigned M = min(cnt[b], (unsigned)KCAND);
    for (int j = t; j < KCAND; j += 256) {
        if (j < (int)M) {
            key[j] = ckey[b * KCAND + j];
            box[j] = cbox[b * KCAND + j];
            lab[j] = clab[b * KCAND + j];
        } else {
            key[j] = 0ULL;
        }
    }
    if (t == 0) bestkey = 0ULL;
    __syncthreads();

    for (int k = 0; k < MAXDET; ++k) {
        unsigned long long m = 0ULL;
#pragma unroll
        for (int s = 0; s < KCAND / 256; ++s) {
            unsigned long long v = key[t + s * 256];
            if (v > m) m = v;
        }
#pragma unroll
        for (int off = 32; off >= 1; off >>= 1) {
            unsigned long long o = __shfl_xor(m, off, 64);
            if (o > m) m = o;
        }
        if ((t & 63) == 0) atomicMax(&bestkey, m);
        __syncthreads();  // B1
        unsigned long long bk = bestkey;
        if (bk) {
#pragma unroll
            for (int s = 0; s < KCAND / 256; ++s) {
                int j = t + s * 256;
                if (key[j] == bk) {  // unique match (idx embedded in key)
                    bestbox = box[j];
                    bestlab = lab[j];
                    key[j] = 0ULL;  // reference always kills the selected slot
                }
            }
        }
        __syncthreads();  // B2
        if (bk) {
#pragma clang fp contract(off)
            float4 bb = bestbox;
            float areaB = (bb.z - bb.x) * (bb.w - bb.y);
#pragma unroll
            for (int s = 0; s < KCAND / 256; ++s) {
                int j = t + s * 256;
                unsigned long long kj = key[j];
                if (kj) {
                    float4 bj = box[j];
                    float x1 = fmaxf(bb.x, bj.x), y1 = fmaxf(bb.y, bj.y);
                    float x2 = fminf(bb.z, bj.z), y2 = fminf(bb.w, bj.w);
                    float inter = fmaxf(x2 - x1, 0.0f) * fmaxf(y2 - y1, 0.0f);
                    float areaJ = (bj.z - bj.x) * (bj.w - bj.y);
                    float iou = inter / (areaB + areaJ - inter + 1e-8f);
                    if (iou > IOUT) key[j] = 0ULL;
                }
            }
        }
        if (t == 0) {
            if (bk) {
                out_s[k] = __uint_as_float((unsigned)(bk >> 32));
                out_l[k] = (float)bestlab;
                out_b[k] = bestbox;
            } else {
                out_s[k] = 0.0f;
                out_l[k] = -1.0f;
                out_b[k] = make_float4(0.f, 0.f, 0.f, 0.f);
            }
            bestkey = 0ULL;
        }
        __syncthreads();  // B3
    }

    if (t < MAXDET) {
        out[b * MAXDET + t] = out_s[t];
        out[NB * MAXDET + b * MAXDET + t] = out_l[t];
    }
    for (int j = t; j < MAXDET * 4; j += 256) {
        int d = j >> 2, c = j & 3;
        float4 bb = out_b[d];
        float v = (c == 0) ? bb.x : (c == 1) ? bb.y : (c == 2) ? bb.z : bb.w;
        out[2 * NB * MAXDET + (size_t)(b * MAXDET + d) * 4 + c] = v;
    }
}

extern "C" void kernel_launch(void* const* d_in, const int* in_sizes, int n_in,
                              void* d_out, int out_size, void* d_ws, size_t ws_size,
                              hipStream_t stream) {
    const float* reg = (const float*)d_in[0];  // [8,100000,4]
    const float* cls = (const float*)d_in[1];  // [8,100000,90]
    const float* anc = (const float*)d_in[2];  // [1,100000,4]

    char* ws = (char*)d_ws;
    float4* ws_box            = (float4*)(ws + OFF_BOX);
    float* ws_score           = (float*)(ws + OFF_SCORE);
    unsigned char* ws_label   = (unsigned char*)(ws + OFF_LABEL);
    unsigned* hrows           = (unsigned*)(ws + OFF_HROWS);
    unsigned* thr_bin         = (unsigned*)(ws + OFF_THR);
    unsigned* cnt             = (unsigned*)(ws + OFF_CNT);
    unsigned long long* ckey  = (unsigned long long*)(ws + OFF_CKEY);
    float4* cbox              = (float4*)(ws + OFF_CBOX);
    int* clab                 = (int*)(ws + OFF_CLAB);

    float* out = (float*)d_out;

    k_score_box<<<NB * NA / 16, 256, 0, stream>>>(cls, reg, anc, ws_box, ws_score, ws_label);
    k_hist<<<dim3(NBLK, NB), 256, 0, stream>>>(ws_score, hrows);
    k_thresh<<<NB, 256, 0, stream>>>(hrows, thr_bin, cnt);
    k_compact<<<dim3(NBLK, NB), 256, 0, stream>>>(ws_score, ws_label, ws_box, thr_bin, cnt,
                                                  ckey, cbox, clab);
    k_nms<<<NB, 256, 0, stream>>>(ckey, cbox, clab, cnt, out);
}

// Round 4
// 608.018 us; speedup vs baseline: 1.6946x; 1.1415x over previous
//
#include <hip/hip_runtime.h>

#define NB 8
#define NA 100000
#define NC 90
#define MAXDET 100
#define KCAND 2048
#define NBINS 4096
#define NBLK 13        // hist/compact blocks per image
#define BLK_ANCH 8000  // anchors per hist/compact block
#define ABLK 128       // anchors per score_box block
#define MASK_WORDS 32  // u64 words per mask row (2048 bits)
#define CH_ROWS 64     // scan chunk rows (one 64-candidate group per chunk)
#define CONF 0.25f
#define IOUT 0.45f

// ---- workspace layout (bytes), total ~10.5 MiB ----
static constexpr size_t OFF_SCORE = 0;                                           // NB*NA f32
static constexpr size_t OFF_LABEL = OFF_SCORE + (size_t)NB * NA * 4;             // NB*NA u8
static constexpr size_t OFF_HROWS = OFF_LABEL + (size_t)NB * NA;                 // NB*NBLK*NBINS u32
static constexpr size_t OFF_THR   = OFF_HROWS + (size_t)NB * NBLK * NBINS * 4;   // NB u32 (pad 64)
static constexpr size_t OFF_CNT   = OFF_THR + 64;                                // NB u32 (pad 64)
static constexpr size_t OFF_CKEY  = OFF_CNT + 64;                                // NB*KCAND u64
static constexpr size_t OFF_SSC   = OFF_CKEY + (size_t)NB * KCAND * 8;           // NB*KCAND f32
static constexpr size_t OFF_SLAB  = OFF_SSC + (size_t)NB * KCAND * 4;            // NB*KCAND i32
static constexpr size_t OFF_SBOX  = OFF_SLAB + (size_t)NB * KCAND * 4;           // NB*KCAND float4
static constexpr size_t OFF_MASK  = OFF_SBOX + (size_t)NB * KCAND * 16;          // NB*KCAND*32 u64

__device__ __forceinline__ float4 decode_clip(float4 a, float4 r) {
#pragma clang fp contract(off)
    // a = (y1,x1,y2,x2) anchor; r = (dy,dx,dh,dw)
    float yca = (a.x + a.z) * 0.5f;
    float xca = (a.y + a.w) * 0.5f;
    float ha  = a.z - a.x;
    float wa  = a.w - a.y;
    float w   = expf(r.w) * wa;
    float h   = expf(r.z) * ha;
    float yc  = r.x * ha + yca;
    float xc  = r.y * wa + xca;
    float x1  = xc - w * 0.5f, y1 = yc - h * 0.5f;
    float x2  = xc + w * 0.5f, y2 = yc + h * 0.5f;
    x1 = fminf(fmaxf(x1, 0.0f), 512.0f);
    x2 = fminf(fmaxf(x2, 0.0f), 512.0f);
    y1 = fminf(fmaxf(y1, 0.0f), 512.0f);
    y2 = fminf(fmaxf(y2, 0.0f), 512.0f);
    return make_float4(x1, y1, x2, y2);
}

// LDS-transpose score kernel: 128 anchors/block staged with stride-1 float4 loads,
// then 2 threads per anchor reduce 45 classes each from LDS (45-dword stride -> free 2-way).
__global__ __launch_bounds__(256) void k_score_box(const float* __restrict__ cls,
                                                   float* __restrict__ ws_score,
                                                   unsigned char* __restrict__ ws_label) {
    __shared__ float tile[ABLK * NC];  // 45 KB
    int t = threadIdx.x;
    const float4* g4 = (const float4*)(cls + (size_t)blockIdx.x * (ABLK * NC));
    float4* t4 = (float4*)tile;
    for (int i = t; i < ABLK * NC / 4; i += 256) t4[i] = g4[i];
    __syncthreads();

    int la = t >> 1, h = t & 1;
    const float* row = tile + la * NC + h * 45;
    int jbase = NC - 1 - h * 45;
    unsigned long long best = 0ULL;
    for (int j2 = 0; j2 < 45; ++j2) {
        float x = row[j2];
        float s = 1.0f / (1.0f + expf(-x));  // same formula as verified rounds 2-3
        unsigned long long key = ((unsigned long long)__float_as_uint(s) << 32) |
                                 (unsigned long long)(unsigned)(jbase - j2);
        if (key > best) best = key;
    }
    unsigned long long o = __shfl_xor(best, 1, 64);
    if (o > best) best = o;
    if (h == 0) {
        int a = blockIdx.x * ABLK + la;
        ws_score[a] = __uint_as_float((unsigned)(best >> 32));
        ws_label[a] = (unsigned char)(NC - 1 - (unsigned)(best & 0xFFFFFFFFu));
    }
}

// Per-block LDS histogram, full-row writeout (no global atomics).
__global__ __launch_bounds__(256) void k_hist(const float* __restrict__ ws_score,
                                              unsigned* __restrict__ hrows) {
    __shared__ unsigned h[NBINS];
    int b = blockIdx.y, blk = blockIdx.x, tid = threadIdx.x;
    for (int i = tid; i < NBINS; i += 256) h[i] = 0u;
    __syncthreads();
    int base = blk * BLK_ANCH;
    int lim = min(BLK_ANCH, NA - base);
    const float* sc = ws_score + (size_t)b * NA + base;
    for (int i = tid; i < lim; i += 256) {
        float s = sc[i];
        if (s > CONF) {
            int bin = min((int)(s * (float)NBINS), NBINS - 1);
            atomicAdd(&h[bin], 1u);
        }
    }
    __syncthreads();
    unsigned* row = hrows + ((size_t)b * NBLK + blk) * NBINS;
    for (int i = tid; i < NBINS; i += 256) row[i] = h[i];
}

// One block per image: reduce rows, min bin with suffix-count <= KCAND; zero cnt.
__global__ __launch_bounds__(256) void k_thresh(const unsigned* __restrict__ hrows,
                                                unsigned* __restrict__ thr_bin,
                                                unsigned* __restrict__ cnt) {
    __shared__ unsigned h[NBINS];
    __shared__ unsigned chunk[256];
    __shared__ int bstar;
    int b = blockIdx.x, t = threadIdx.x;
    for (int i = t; i < NBINS; i += 256) {
        unsigned s = 0;
        for (int r = 0; r < NBLK; ++r) s += hrows[((size_t)b * NBLK + r) * NBINS + i];
        h[i] = s;
    }
    if (t == 0) { bstar = NBINS - 1; cnt[b] = 0u; }
    __syncthreads();
    unsigned s = 0;
    for (int j = 0; j < 16; ++j) s += h[t * 16 + j];
    chunk[t] = s;
    __syncthreads();
    unsigned U = 0;
    for (int j = t + 1; j < 256; ++j) U += chunk[j];
    unsigned run = U;
    int cand = NBINS;
    for (int j = 15; j >= 0; --j) {
        run += h[t * 16 + j];
        if (run <= (unsigned)KCAND) cand = t * 16 + j;
    }
    if (cand < NBINS) atomicMin(&bstar, cand);
    __syncthreads();
    if (t == 0) thr_bin[b] = (unsigned)bstar;
}

// Block-aggregated compaction: writes packed keys only (idx embedded). One atomic/block.
__global__ __launch_bounds__(256) void k_compact(const float* __restrict__ ws_score,
                                                 const unsigned* __restrict__ thr_bin,
                                                 unsigned* __restrict__ cnt,
                                                 unsigned long long* __restrict__ ckey) {
    __shared__ unsigned scan[256];
    __shared__ unsigned base_s;
    int b = blockIdx.y, blk = blockIdx.x, t = threadIdx.x;
    int base = blk * BLK_ANCH;
    int lim = min(BLK_ANCH, NA - base);
    size_t ibase = (size_t)b * NA + base;
    unsigned thr = thr_bin[b];

    unsigned c = 0;
    for (int i = t; i < lim; i += 256) {
        float s = ws_score[ibase + i];
        if (s > CONF) {
            int bin = min((int)(s * (float)NBINS), NBINS - 1);
            if ((unsigned)bin >= thr) c++;
        }
    }
    scan[t] = c;
    __syncthreads();
    for (int off = 1; off < 256; off <<= 1) {
        unsigned v = (t >= off) ? scan[t - off] : 0u;
        __syncthreads();
        scan[t] += v;
        __syncthreads();
    }
    if (t == 255) base_s = atomicAdd(&cnt[b], scan[255]);
    __syncthreads();
    unsigned pos = base_s + scan[t] - c;
    for (int i = t; i < lim; i += 256) {
        float s = ws_score[ibase + i];
        if (s > CONF) {
            int bin = min((int)(s * (float)NBINS), NBINS - 1);
            if ((unsigned)bin >= thr) {
                unsigned p = pos++;
                if (p < (unsigned)KCAND) {
                    int n = base + i;
                    ckey[(size_t)b * KCAND + p] =
                        ((unsigned long long)__float_as_uint(s) << 32) |
                        (unsigned long long)(0xFFFFFFFFu - (unsigned)n);
                }
            }
        }
    }
}

// One block per image: bitonic sort 2048 keys descending in LDS, then decode the
// 2048 surviving boxes (gather reg/anc) and emit sorted score/label/box arrays.
__global__ __launch_bounds__(256) void k_sortdecode(const unsigned long long* __restrict__ ckey,
                                                    const unsigned* __restrict__ cnt,
                                                    const unsigned char* __restrict__ ws_label,
                                                    const float* __restrict__ reg,
                                                    const float* __restrict__ anc,
                                                    float* __restrict__ sscore,
                                                    int* __restrict__ slab,
                                                    float4* __restrict__ sbox) {
    __shared__ unsigned long long key[KCAND];  // 16 KB
    int b = blockIdx.x, t = threadIdx.x;
    unsigned M = min(cnt[b], (unsigned)KCAND);
    for (int i = t; i < KCAND; i += 256)
        key[i] = (i < (int)M) ? ckey[(size_t)b * KCAND + i] : 0ULL;
    __syncthreads();
    for (int k = 2; k <= KCAND; k <<= 1) {
        for (int j = k >> 1; j > 0; j >>= 1) {
            for (int s = 0; s < KCAND / 256; ++s) {
                int p = t + s * 256;
                int q = p ^ j;
                if (q > p) {
                    unsigned long long a = key[p], bb = key[q];
                    bool desc = ((p & k) == 0);
                    if (desc ? (a < bb) : (a > bb)) { key[p] = bb; key[q] = a; }
                }
            }
            __syncthreads();
        }
    }
    for (int i = t; i < KCAND; i += 256) {
        unsigned long long kk = key[i];
        size_t o = (size_t)b * KCAND + i;
        if (kk != 0ULL) {
            unsigned n = 0xFFFFFFFFu - (unsigned)(kk & 0xFFFFFFFFu);
            sscore[o] = __uint_as_float((unsigned)(kk >> 32));
            slab[o] = (int)ws_label[(size_t)b * NA + n];
            float4 a4 = ((const float4*)anc)[n];
            float4 r4 = ((const float4*)reg)[(size_t)b * NA + n];
            sbox[o] = decode_clip(a4, r4);
        } else {
            sscore[o] = 0.0f;
            slab[o] = -1;
            sbox[o] = make_float4(0.f, 0.f, 0.f, 0.f);
        }
    }
}

// Pairwise suppression bitmask: block = 8 rows x 32 words; thread = 64 IoUs.
__global__ __launch_bounds__(256) void k_mask(const float4* __restrict__ sbox,
                                              unsigned long long* __restrict__ mask) {
    __shared__ float4 bx[KCAND];  // 32 KB
    int b = blockIdx.y, t = threadIdx.x;
    for (int i = t; i < KCAND; i += 256) bx[i] = sbox[(size_t)b * KCAND + i];
    __syncthreads();
    int r = t >> 5, w = t & 31;
    int row = blockIdx.x * 8 + r;
    float4 rb = bx[row];
    unsigned long long bits = 0ULL;
    {
#pragma clang fp contract(off)
        float areaR = (rb.z - rb.x) * (rb.w - rb.y);
        int cbase = w * 64;
        for (int cc = 0; cc < 64; ++cc) {
            float4 cb = bx[cbase + cc];
            float x1 = fmaxf(rb.x, cb.x), y1 = fmaxf(rb.y, cb.y);
            float x2 = fminf(rb.z, cb.z), y2 = fminf(rb.w, cb.w);
            float inter = fmaxf(x2 - x1, 0.0f) * fmaxf(y2 - y1, 0.0f);
            float areaC = (cb.z - cb.x) * (cb.w - cb.y);
            float iou = inter / (areaR + areaC - inter + 1e-8f);
            if (iou > IOUT) bits |= (1ULL << cc);
        }
    }
    mask[((size_t)b * KCAND + row) * MASK_WORDS + w] = bits;
}

// One block per image. Greedy scan over sorted candidates using the bitmask.
// removed bitmask in wave-0 registers (lane j owns word j). Mask rows streamed
// through double-buffered LDS; waves 1-3 + pipeline hide the load latency.
__global__ __launch_bounds__(256) void k_scan(const unsigned long long* __restrict__ mask,
                                              const unsigned* __restrict__ cnt,
                                              const float* __restrict__ sscore,
                                              const int* __restrict__ slab,
                                              const float4* __restrict__ sbox,
                                              float* __restrict__ out) {
    __shared__ unsigned long long buf[2][CH_ROWS * MASK_WORDS];  // 2 x 16 KB
    __shared__ int picks[MAXDET];
    __shared__ int npick_s;
    __shared__ int done_s;

    int b = blockIdx.x, t = threadIdx.x;
    unsigned M = min(cnt[b], (unsigned)KCAND);
    const unsigned long long* mbase = mask + (size_t)b * KCAND * MASK_WORDS;

    if (t == 0) { npick_s = 0; done_s = 0; }
    for (int i = t; i < CH_ROWS * MASK_WORDS; i += 256) buf[0][i] = mbase[i];
    __syncthreads();

    unsigned long long removed = 0ULL;  // wave0 lane j<32 owns word j
    int npick = 0;

    for (int q = 0; q < KCAND / CH_ROWS; ++q) {
        int cur = q & 1;
        bool havepre = (q + 1 < KCAND / CH_ROWS) && !done_s;
        unsigned long long pre[CH_ROWS * MASK_WORDS / 256];
        if (havepre) {
            const unsigned long long* src = mbase + (size_t)(q + 1) * CH_ROWS * MASK_WORDS;
#pragma unroll
            for (int s = 0; s < CH_ROWS * MASK_WORDS / 256; ++s) pre[s] = src[t + s * 256];
        }
        if (t < 64) {
            const unsigned long long* ch = buf[cur];
            int gstart = q * 64;  // one group per chunk
            if (gstart < (int)M && npick < MAXDET) {
                int vg = (int)M - gstart;
                unsigned long long valid = (vg >= 64) ? ~0ULL : ((1ULL << vg) - 1ULL);
                while (npick < MAXDET) {
                    unsigned long long rg = __shfl(removed, q, 64);
                    unsigned long long free = ~rg & valid;
                    if (free == 0ULL) break;
                    int cl = __ffsll((long long)free) - 1;
                    int c = gstart + cl;
                    if (t == 0) picks[npick] = c;
                    npick++;
                    if (t == q) removed |= (1ULL << cl);           // self-kill (zero-area safe)
                    if (t < 32) removed |= ch[cl * MASK_WORDS + t];  // OR suppression row
                }
            }
            if (t == 0) {
                npick_s = npick;
                done_s = (npick >= MAXDET || (q + 1) * CH_ROWS >= (int)M) ? 1 : 0;
            }
        }
        if (havepre) {
#pragma unroll
            for (int s = 0; s < CH_ROWS * MASK_WORDS / 256; ++s)
                buf[1 - cur][t + s * 256] = pre[s];
        }
        __syncthreads();
        if (done_s) break;
    }

    __syncthreads();
    int np = npick_s;
    for (int k = t; k < MAXDET; k += 256) {
        float sc = 0.0f, lb = -1.0f;
        float4 bb = make_float4(0.f, 0.f, 0.f, 0.f);
        if (k < np) {
            int i = picks[k];
            size_t o = (size_t)b * KCAND + i;
            sc = sscore[o];
            lb = (float)slab[o];
            bb = sbox[o];
        }
        out[b * MAXDET + k] = sc;
        out[NB * MAXDET + b * MAXDET + k] = lb;
        ((float4*)(out + 2 * NB * MAXDET))[b * MAXDET + k] = bb;
    }
}

extern "C" void kernel_launch(void* const* d_in, const int* in_sizes, int n_in,
                              void* d_out, int out_size, void* d_ws, size_t ws_size,
                              hipStream_t stream) {
    const float* reg = (const float*)d_in[0];  // [8,100000,4]
    const float* cls = (const float*)d_in[1];  // [8,100000,90]
    const float* anc = (const float*)d_in[2];  // [1,100000,4]

    char* ws = (char*)d_ws;
    float* ws_score           = (float*)(ws + OFF_SCORE);
    unsigned char* ws_label   = (unsigned char*)(ws + OFF_LABEL);
    unsigned* hrows           = (unsigned*)(ws + OFF_HROWS);
    unsigned* thr_bin         = (unsigned*)(ws + OFF_THR);
    unsigned* cnt             = (unsigned*)(ws + OFF_CNT);
    unsigned long long* ckey  = (unsigned long long*)(ws + OFF_CKEY);
    float* sscore             = (float*)(ws + OFF_SSC);
    int* slab                 = (int*)(ws + OFF_SLAB);
    float4* sbox              = (float4*)(ws + OFF_SBOX);
    unsigned long long* maskp = (unsigned long long*)(ws + OFF_MASK);

    float* out = (float*)d_out;

    k_score_box<<<NB * NA / ABLK, 256, 0, stream>>>(cls, ws_score, ws_label);
    k_hist<<<dim3(NBLK, NB), 256, 0, stream>>>(ws_score, hrows);
    k_thresh<<<NB, 256, 0, stream>>>(hrows, thr_bin, cnt);
    k_compact<<<dim3(NBLK, NB), 256, 0, stream>>>(ws_score, thr_bin, cnt, ckey);
    k_sortdecode<<<NB, 256, 0, stream>>>(ckey, cnt, ws_label, reg, anc, sscore, slab, sbox);
    k_mask<<<dim3(KCAND / 8, NB), 256, 0, stream>>>(sbox, maskp);
    k_scan<<<NB, 256, 0, stream>>>(maskp, cnt, sscore, slab, sbox, out);
}

// Round 5
// 580.661 us; speedup vs baseline: 1.7744x; 1.0471x over previous
//
#include <hip/hip_runtime.h>

#define NB 8
#define NA 100000
#define NC 90
#define MAXDET 100
#define KCAND 2048
#define NBINS 4096
#define NBLK 13        // hist/compact blocks per image
#define BLK_ANCH 8000  // anchors per hist/compact block
#define ABLK 64        // anchors per score_box block (22.5 KB LDS -> 7 blocks/CU)
#define MASK_WORDS 32  // u64 words per mask row (2048 bits)
#define CONF 0.25f
#define IOUT 0.45f

// ---- workspace layout (bytes), total ~10.5 MiB ----
static constexpr size_t OFF_SCORE = 0;                                           // NB*NA f32
static constexpr size_t OFF_LABEL = OFF_SCORE + (size_t)NB * NA * 4;             // NB*NA u8
static constexpr size_t OFF_HROWS = OFF_LABEL + (size_t)NB * NA;                 // NB*NBLK*NBINS u32
static constexpr size_t OFF_THR   = OFF_HROWS + (size_t)NB * NBLK * NBINS * 4;   // NB u32 (pad 64)
static constexpr size_t OFF_CNT   = OFF_THR + 64;                                // NB u32 (pad 64)
static constexpr size_t OFF_CKEY  = OFF_CNT + 64;                                // NB*KCAND u64
static constexpr size_t OFF_SSC   = OFF_CKEY + (size_t)NB * KCAND * 8;           // NB*KCAND f32
static constexpr size_t OFF_SLAB  = OFF_SSC + (size_t)NB * KCAND * 4;            // NB*KCAND i32
static constexpr size_t OFF_SBOX  = OFF_SLAB + (size_t)NB * KCAND * 4;           // NB*KCAND float4
static constexpr size_t OFF_MASK  = OFF_SBOX + (size_t)NB * KCAND * 16;          // NB*KCAND*32 u64

__device__ __forceinline__ float4 decode_clip(float4 a, float4 r) {
#pragma clang fp contract(off)
    // a = (y1,x1,y2,x2) anchor; r = (dy,dx,dh,dw)
    float yca = (a.x + a.z) * 0.5f;
    float xca = (a.y + a.w) * 0.5f;
    float ha  = a.z - a.x;
    float wa  = a.w - a.y;
    float w   = expf(r.w) * wa;
    float h   = expf(r.z) * ha;
    float yc  = r.x * ha + yca;
    float xc  = r.y * wa + xca;
    float x1  = xc - w * 0.5f, y1 = yc - h * 0.5f;
    float x2  = xc + w * 0.5f, y2 = yc + h * 0.5f;
    x1 = fminf(fmaxf(x1, 0.0f), 512.0f);
    x2 = fminf(fmaxf(x2, 0.0f), 512.0f);
    y1 = fminf(fmaxf(y1, 0.0f), 512.0f);
    y2 = fminf(fmaxf(y2, 0.0f), 512.0f);
    return make_float4(x1, y1, x2, y2);
}

// LDS-transpose score kernel: 64 anchors/block (22.5 KB -> 7 blocks/CU), stride-1 float4
// staging, then 4 threads/anchor reduce 23/23/22/22 classes from LDS, shfl-xor combine.
__global__ __launch_bounds__(256) void k_score_box(const float* __restrict__ cls,
                                                   float* __restrict__ ws_score,
                                                   unsigned char* __restrict__ ws_label) {
    __shared__ float tile[ABLK * NC];  // 22.5 KB
    int t = threadIdx.x;
    const float4* g4 = (const float4*)(cls + (size_t)blockIdx.x * (ABLK * NC));
    float4* t4 = (float4*)tile;
#pragma unroll
    for (int i = t; i < ABLK * NC / 4; i += 256) t4[i] = g4[i];
    __syncthreads();

    int la = t >> 2, h = t & 3;
    int off = h * 22 + (h < 2 ? h : 2);  // 0,23,46,68
    int len = (h < 2) ? 23 : 22;
    const float* row = tile + la * NC + off;
    unsigned long long best = 0ULL;
    for (int i = 0; i < len; ++i) {
        float x = row[i];
        float s = 1.0f / (1.0f + expf(-x));  // same formula as verified rounds 2-4
        unsigned long long key = ((unsigned long long)__float_as_uint(s) << 32) |
                                 (unsigned long long)(unsigned)(NC - 1 - (off + i));
        if (key > best) best = key;
    }
    unsigned long long o = __shfl_xor(best, 1, 64);
    if (o > best) best = o;
    o = __shfl_xor(best, 2, 64);
    if (o > best) best = o;
    if (h == 0) {
        int a = blockIdx.x * ABLK + la;
        ws_score[a] = __uint_as_float((unsigned)(best >> 32));
        ws_label[a] = (unsigned char)(NC - 1 - (unsigned)(best & 0xFFFFFFFFu));
    }
}

// Per-block LDS histogram, full-row writeout (no global atomics).
__global__ __launch_bounds__(256) void k_hist(const float* __restrict__ ws_score,
                                              unsigned* __restrict__ hrows) {
    __shared__ unsigned h[NBINS];
    int b = blockIdx.y, blk = blockIdx.x, tid = threadIdx.x;
    for (int i = tid; i < NBINS; i += 256) h[i] = 0u;
    __syncthreads();
    int base = blk * BLK_ANCH;
    int lim = min(BLK_ANCH, NA - base);
    const float* sc = ws_score + (size_t)b * NA + base;
    for (int i = tid; i < lim; i += 256) {
        float s = sc[i];
        if (s > CONF) {
            int bin = min((int)(s * (float)NBINS), NBINS - 1);
            atomicAdd(&h[bin], 1u);
        }
    }
    __syncthreads();
    unsigned* row = hrows + ((size_t)b * NBLK + blk) * NBINS;
    for (int i = tid; i < NBINS; i += 256) row[i] = h[i];
}

// One block per image: reduce rows, min bin with suffix-count <= KCAND; zero cnt.
__global__ __launch_bounds__(256) void k_thresh(const unsigned* __restrict__ hrows,
                                                unsigned* __restrict__ thr_bin,
                                                unsigned* __restrict__ cnt) {
    __shared__ unsigned h[NBINS];
    __shared__ unsigned chunk[256];
    __shared__ int bstar;
    int b = blockIdx.x, t = threadIdx.x;
    for (int i = t; i < NBINS; i += 256) {
        unsigned s = 0;
        for (int r = 0; r < NBLK; ++r) s += hrows[((size_t)b * NBLK + r) * NBINS + i];
        h[i] = s;
    }
    if (t == 0) { bstar = NBINS - 1; cnt[b] = 0u; }
    __syncthreads();
    unsigned s = 0;
    for (int j = 0; j < 16; ++j) s += h[t * 16 + j];
    chunk[t] = s;
    __syncthreads();
    unsigned U = 0;
    for (int j = t + 1; j < 256; ++j) U += chunk[j];
    unsigned run = U;
    int cand = NBINS;
    for (int j = 15; j >= 0; --j) {
        run += h[t * 16 + j];
        if (run <= (unsigned)KCAND) cand = t * 16 + j;
    }
    if (cand < NBINS) atomicMin(&bstar, cand);
    __syncthreads();
    if (t == 0) thr_bin[b] = (unsigned)bstar;
}

// Block-aggregated compaction: writes packed keys only (idx embedded). One atomic/block.
__global__ __launch_bounds__(256) void k_compact(const float* __restrict__ ws_score,
                                                 const unsigned* __restrict__ thr_bin,
                                                 unsigned* __restrict__ cnt,
                                                 unsigned long long* __restrict__ ckey) {
    __shared__ unsigned scan[256];
    __shared__ unsigned base_s;
    int b = blockIdx.y, blk = blockIdx.x, t = threadIdx.x;
    int base = blk * BLK_ANCH;
    int lim = min(BLK_ANCH, NA - base);
    size_t ibase = (size_t)b * NA + base;
    unsigned thr = thr_bin[b];

    unsigned c = 0;
    for (int i = t; i < lim; i += 256) {
        float s = ws_score[ibase + i];
        if (s > CONF) {
            int bin = min((int)(s * (float)NBINS), NBINS - 1);
            if ((unsigned)bin >= thr) c++;
        }
    }
    scan[t] = c;
    __syncthreads();
    for (int off = 1; off < 256; off <<= 1) {
        unsigned v = (t >= off) ? scan[t - off] : 0u;
        __syncthreads();
        scan[t] += v;
        __syncthreads();
    }
    if (t == 255) base_s = atomicAdd(&cnt[b], scan[255]);
    __syncthreads();
    unsigned pos = base_s + scan[t] - c;
    for (int i = t; i < lim; i += 256) {
        float s = ws_score[ibase + i];
        if (s > CONF) {
            int bin = min((int)(s * (float)NBINS), NBINS - 1);
            if ((unsigned)bin >= thr) {
                unsigned p = pos++;
                if (p < (unsigned)KCAND) {
                    int n = base + i;
                    ckey[(size_t)b * KCAND + p] =
                        ((unsigned long long)__float_as_uint(s) << 32) |
                        (unsigned long long)(0xFFFFFFFFu - (unsigned)n);
                }
            }
        }
    }
}

// One 1024-thread block per image: bitonic sort 2048 keys descending (16 waves to
// amortize the 66 barriers), then decode surviving boxes.
__global__ __launch_bounds__(1024) void k_sortdecode(const unsigned long long* __restrict__ ckey,
                                                     const unsigned* __restrict__ cnt,
                                                     const unsigned char* __restrict__ ws_label,
                                                     const float* __restrict__ reg,
                                                     const float* __restrict__ anc,
                                                     float* __restrict__ sscore,
                                                     int* __restrict__ slab,
                                                     float4* __restrict__ sbox) {
    __shared__ unsigned long long key[KCAND];  // 16 KB
    int b = blockIdx.x, t = threadIdx.x;
    unsigned M = min(cnt[b], (unsigned)KCAND);
    for (int i = t; i < KCAND; i += 1024)
        key[i] = (i < (int)M) ? ckey[(size_t)b * KCAND + i] : 0ULL;
    __syncthreads();
    for (int k = 2; k <= KCAND; k <<= 1) {
        for (int j = k >> 1; j > 0; j >>= 1) {
#pragma unroll
            for (int s = 0; s < KCAND / 1024; ++s) {
                int p = t + s * 1024;
                int q = p ^ j;
                if (q > p) {
                    unsigned long long a = key[p], bb = key[q];
                    bool desc = ((p & k) == 0);
                    if (desc ? (a < bb) : (a > bb)) { key[p] = bb; key[q] = a; }
                }
            }
            __syncthreads();
        }
    }
    for (int i = t; i < KCAND; i += 1024) {
        unsigned long long kk = key[i];
        size_t o = (size_t)b * KCAND + i;
        if (kk != 0ULL) {
            unsigned n = 0xFFFFFFFFu - (unsigned)(kk & 0xFFFFFFFFu);
            sscore[o] = __uint_as_float((unsigned)(kk >> 32));
            slab[o] = (int)ws_label[(size_t)b * NA + n];
            float4 a4 = ((const float4*)anc)[n];
            float4 r4 = ((const float4*)reg)[(size_t)b * NA + n];
            sbox[o] = decode_clip(a4, r4);
        } else {
            sscore[o] = 0.0f;
            slab[o] = -1;
            sbox[o] = make_float4(0.f, 0.f, 0.f, 0.f);
        }
    }
}

// Pairwise suppression bitmask: block = 8 rows x 32 words; thread = 64 IoUs.
__global__ __launch_bounds__(256) void k_mask(const float4* __restrict__ sbox,
                                              unsigned long long* __restrict__ mask) {
    __shared__ float4 bx[KCAND];  // 32 KB
    int b = blockIdx.y, t = threadIdx.x;
    for (int i = t; i < KCAND; i += 256) bx[i] = sbox[(size_t)b * KCAND + i];
    __syncthreads();
    int r = t >> 5, w = t & 31;
    int row = blockIdx.x * 8 + r;
    float4 rb = bx[row];
    unsigned long long bits = 0ULL;
    {
#pragma clang fp contract(off)
        float areaR = (rb.z - rb.x) * (rb.w - rb.y);
        int cbase = w * 64;
        for (int cc = 0; cc < 64; ++cc) {
            float4 cb = bx[cbase + cc];
            float x1 = fmaxf(rb.x, cb.x), y1 = fmaxf(rb.y, cb.y);
            float x2 = fminf(rb.z, cb.z), y2 = fminf(rb.w, cb.w);
            float inter = fmaxf(x2 - x1, 0.0f) * fmaxf(y2 - y1, 0.0f);
            float areaC = (cb.z - cb.x) * (cb.w - cb.y);
            float iou = inter / (areaR + areaC - inter + 1e-8f);
            if (iou > IOUT) bits |= (1ULL << cc);
        }
    }
    mask[((size_t)b * KCAND + row) * MASK_WORDS + w] = bits;
}

// One wave per image. Greedy scan via register bitmask (lane l owns removed word l);
// per pick: ballot -> ffs -> one coalesced 256B row load -> OR. Reads only picked rows.
__global__ __launch_bounds__(64) void k_scan(const unsigned long long* __restrict__ mask,
                                             const unsigned* __restrict__ cnt,
                                             const float* __restrict__ sscore,
                                             const int* __restrict__ slab,
                                             const float4* __restrict__ sbox,
                                             float* __restrict__ out) {
    __shared__ int picks[MAXDET];
    int b = blockIdx.x, l = threadIdx.x;
    unsigned M = min(cnt[b], (unsigned)KCAND);
    const unsigned long long* mb = mask + (size_t)b * KCAND * MASK_WORDS;

    unsigned long long valid = 0ULL;
    if (l < 32) {
        int rem = (int)M - l * 64;
        valid = (rem >= 64) ? ~0ULL : ((rem > 0) ? ((1ULL << rem) - 1ULL) : 0ULL);
    }
    unsigned long long removed = 0ULL;
    int np = 0;
    while (np < MAXDET) {
        unsigned long long free = valid & ~removed;
        unsigned long long act = __ballot(free != 0ULL);
        if (act == 0ULL) break;
        int lstar = __ffsll((long long)act) - 1;
        unsigned long long fw = __shfl(free, lstar, 64);
        int bit = __ffsll((long long)fw) - 1;
        int c = lstar * 64 + bit;
        if (l == 0) picks[np] = c;
        np++;
        if (l == lstar) removed |= (1ULL << bit);  // self-kill (zero-area safe)
        if (l < 32) removed |= mb[(size_t)c * MASK_WORDS + l];
    }
    __syncthreads();

    for (int k = l; k < MAXDET; k += 64) {
        float sc = 0.0f, lb = -1.0f;
        float4 bb = make_float4(0.f, 0.f, 0.f, 0.f);
        if (k < np) {
            int i = picks[k];
            size_t o = (size_t)b * KCAND + i;
            sc = sscore[o];
            lb = (float)slab[o];
            bb = sbox[o];
        }
        out[b * MAXDET + k] = sc;
        out[NB * MAXDET + b * MAXDET + k] = lb;
        ((float4*)(out + 2 * NB * MAXDET))[b * MAXDET + k] = bb;
    }
}

extern "C" void kernel_launch(void* const* d_in, const int* in_sizes, int n_in,
                              void* d_out, int out_size, void* d_ws, size_t ws_size,
                              hipStream_t stream) {
    const float* reg = (const float*)d_in[0];  // [8,100000,4]
    const float* cls = (const float*)d_in[1];  // [8,100000,90]
    const float* anc = (const float*)d_in[2];  // [1,100000,4]

    char* ws = (char*)d_ws;
    float* ws_score           = (float*)(ws + OFF_SCORE);
    unsigned char* ws_label   = (unsigned char*)(ws + OFF_LABEL);
    unsigned* hrows           = (unsigned*)(ws + OFF_HROWS);
    unsigned* thr_bin         = (unsigned*)(ws + OFF_THR);
    unsigned* cnt             = (unsigned*)(ws + OFF_CNT);
    unsigned long long* ckey  = (unsigned long long*)(ws + OFF_CKEY);
    float* sscore             = (float*)(ws + OFF_SSC);
    int* slab                 = (int*)(ws + OFF_SLAB);
    float4* sbox              = (float4*)(ws + OFF_SBOX);
    unsigned long long* maskp = (unsigned long long*)(ws + OFF_MASK);

    float* out = (float*)d_out;

    k_score_box<<<NB * NA / ABLK, 256, 0, stream>>>(cls, ws_score, ws_label);
    k_hist<<<dim3(NBLK, NB), 256, 0, stream>>>(ws_score, hrows);
    k_thresh<<<NB, 256, 0, stream>>>(hrows, thr_bin, cnt);
    k_compact<<<dim3(NBLK, NB), 256, 0, stream>>>(ws_score, thr_bin, cnt, ckey);
    k_sortdecode<<<NB, 1024, 0, stream>>>(ckey, cnt, ws_label, reg, anc, sscore, slab, sbox);
    k_mask<<<dim3(KCAND / 8, NB), 256, 0, stream>>>(sbox, maskp);
    k_scan<<<NB, 64, 0, stream>>>(maskp, cnt, sscore, slab, sbox, out);
}